// Round 4
// baseline (512.828 us; speedup 1.0000x reference)
//
#include <hip/hip_runtime.h>
#include <hip/hip_bf16.h>

// out[b,k,oc,x] = sum_i W[k,oc,i] * in[b,i,k,x] + bias[k,oc]
// B=4096, Cin=Cout=128, K(offsets)=9, X=9.
// Memory-bound: ~290 MB HBM traffic -> ~46us floor @6.3TB/s.
// R1: XCD swizzle + W direct from global.                (158us)
// R2: deep-MLP staging -> null. Load MLP exonerated.     (164us)
// R3: LDS-relayout coalesced stores -> -13%.             (143us)
// R4: contiguous-read all-k blocks -> +74% REGRESSION (write amplification +
//     barrier-heavy 9-GEMM loop). Load PATTERN exonerated too.
// R5: phase-mixing. Same R3 kernel, BT=8 / 256-thread blocks / 19.6KB LDS ->
//     8 independent blocks per CU (was ~2.5). Theory: all pipes idle because
//     barrier-locked 512-thread blocks march through stage/compute/store in
//     near-lockstep per CU; queues drain between phases. More independent
//     blocks at staggered phases = reads+stores+MFMA concurrently in flight.

#define NB    4096
#define CINC  128
#define COUTC 128
#define NK    9
#define NX    9
#define BT    8                // b's per workgroup
#define NCOL  (BT * NX)        // 72 columns per workgroup
#define LDK   136              // padded row length (shorts): 16B-aligned rows
#define OUTK  (COUTC * NX)     // 1152 floats per (b,k)
#define OUTB  (NK * COUTC * NX)

typedef __attribute__((ext_vector_type(8))) short short8;
typedef __attribute__((ext_vector_type(4))) float floatx4;
typedef __attribute__((ext_vector_type(2))) float floatx2;

__device__ __forceinline__ short f2bf(float f) {
    union { float f; unsigned u; } v; v.f = f;
    unsigned r = v.u + 0x7fff + ((v.u >> 16) & 1);  // RNE; inputs finite normals
    return (short)(r >> 16);
}

__global__ __launch_bounds__(256, 8) void GatherVertical_40656160424516_kernel(
    const float* __restrict__ in, const float* __restrict__ w,
    const float* __restrict__ bias, float* __restrict__ out)
{
    // Aliased LDS: bf16 input tile Il[72][136] (19584 B) during MFMA phase,
    // then float relayout buffer Ol[4][128][9] (18432 B) during the epilogue.
    // 19.6 KB -> 8 blocks/CU (the phase-mixing lever).
    __shared__ __align__(16) char smem[NCOL * LDK * 2];
    short* Il = (short*)smem;
    float* Ol = (float*)smem;

    const int t = threadIdx.x;

    // ---- XCD swizzle: siblings (same btile, k=0..8) land on the same XCD.
    // grid 4608 = 8 XCDs x 576 slots; bijective (4608 % 8 == 0).
    const int j = blockIdx.x;
    const int xcd = j & 7;
    const int slot = j >> 3;          // 0..575 per XCD
    const int grp = slot / 9;         // 0..63
    const int k = slot - grp * 9;     // 0..8
    const int btile = grp * 8 + xcd;  // 0..511
    const int b0 = btile * BT;

    const int lane = t & 63;
    const int wv = t >> 6;            // 0..3; wave owns M-tiles wv and wv+4
    const int lc = lane & 15;
    const int quad = lane >> 4;

    // ---- A-fragments direct from global (L2-resident; shared by all btiles).
    // Two M-tiles per wave: oc_base = wv*16 + m*64.
    const float* wk = w + k * (COUTC * CINC);
    short8 afr[2][4];
    float bsv[2][4];
    #pragma unroll
    for (int m = 0; m < 2; ++m) {
        const int oc_base = wv * 16 + m * 64;
        #pragma unroll
        for (int s = 0; s < 4; ++s) {
            const float* wp = wk + (oc_base + lc) * CINC + s * 32 + quad * 8;
            float4 w0 = *(const float4*)wp;
            float4 w1 = *(const float4*)(wp + 4);
            short8 a;
            a[0] = f2bf(w0.x); a[1] = f2bf(w0.y); a[2] = f2bf(w0.z); a[3] = f2bf(w0.w);
            a[4] = f2bf(w1.x); a[5] = f2bf(w1.y); a[6] = f2bf(w1.z); a[7] = f2bf(w1.w);
            afr[m][s] = a;
        }
        const float* bp = bias + k * COUTC + oc_base + quad * 4;
        #pragma unroll
        for (int r = 0; r < 4; ++r) bsv[m][r] = bp[r];
    }

    // ---- stage input tile: in[b0+bl, i, k, x] -> Il[bl*9+x][i]
    // (R3's proven gather: x fastest across threads, ~transaction-floor)
    const float* inb = in + (size_t)b0 * (CINC * NK * NX) + k * NX;
    #pragma unroll
    for (int it = 0; it < 36; ++it) {
        int f = it * 256 + t;                    // 0..9215
        int bl = f / (CINC * NX);                // /1152 (magic mul)
        int rem = f - bl * (CINC * NX);
        int i = rem / NX;
        int x = rem - i * NX;
        float v = inb[bl * (CINC * NK * NX) + i * (NK * NX) + x];
        Il[(bl * NX + x) * LDK + i] = f2bf(v);
    }

    __syncthreads();

    // ---- MFMA: N=72 as 4 full col-tiles + 1 half tile (cols 64..71; lanes
    // lc>=8 read duplicate col 64+(lc&7), outputs for cols 72..79 never stored).
    floatx4 acc[2][5];
    #pragma unroll
    for (int m = 0; m < 2; ++m)
        #pragma unroll
        for (int n = 0; n < 5; ++n) acc[m][n] = (floatx4){0.f, 0.f, 0.f, 0.f};

    #pragma unroll
    for (int s = 0; s < 4; ++s) {
        int kof = s * 32 + quad * 8;
        #pragma unroll
        for (int n = 0; n < 5; ++n) {
            int col = (n < 4) ? (n * 16 + lc) : (64 + (lc & 7));
            short8 bfr = *(const short8*)&Il[col * LDK + kof];
            acc[0][n] = __builtin_amdgcn_mfma_f32_16x16x32_bf16(afr[0][s], bfr, acc[0][n], 0, 0, 0);
            acc[1][n] = __builtin_amdgcn_mfma_f32_16x16x32_bf16(afr[1][s], bfr, acc[1][n], 0, 0, 0);
        }
    }

    // ---- epilogue: LDS relayout -> fully coalesced stores (R3 scheme).
    // C/D: col(lane&15)=nx -> (bl=nx/9, x=nx%9); row(quad*4+r)=oc offset.
    // Pass p covers bl in [4p, 4p+4): scatter into Ol[bl&3][oc][x], barrier,
    // then wave wv streams row bl=4p+wv (1152 contiguous floats) to global.
    for (int p = 0; p < 2; ++p) {
        __syncthreads();   // p=0: Il reads done; p=1: pass-0 Ol reads done
        #pragma unroll
        for (int n = 0; n < 5; ++n) {
            int nx = n * 16 + lc;
            if (n == 4 && lc >= 8) continue;     // pad cols
            int bl = nx / 9;
            if ((bl >> 2) == p) {
                int x = nx - bl * 9;
                #pragma unroll
                for (int m = 0; m < 2; ++m) {
                    const int oc_base = wv * 16 + m * 64;
                    float* op = Ol + ((bl & 3) * COUTC + oc_base + quad * 4) * NX + x;
                    #pragma unroll
                    for (int r = 0; r < 4; ++r)
                        op[r * NX] = acc[m][n][r] + bsv[m][r];
                }
            }
        }
        __syncthreads();
        const float* src = Ol + wv * OUTK;
        float* dst = out + (size_t)(b0 + p * 4 + wv) * OUTB + k * OUTK;
        #pragma unroll
        for (int s = 0; s < 4; ++s) {
            floatx4 v = *(const floatx4*)(src + s * 256 + lane * 4);
            *(floatx4*)(dst + s * 256 + lane * 4) = v;
        }
        floatx2 v2 = *(const floatx2*)(src + 1024 + lane * 2);
        *(floatx2*)(dst + 1024 + lane * 2) = v2;
    }
}

extern "C" void kernel_launch(void* const* d_in, const int* in_sizes, int n_in,
                              void* d_out, int out_size, void* d_ws, size_t ws_size,
                              hipStream_t stream) {
    const float* in  = (const float*)d_in[0];
    const float* w   = (const float*)d_in[1];
    const float* bs  = (const float*)d_in[2];
    float* out = (float*)d_out;
    dim3 grid((NB / BT) * NK);   // 4608 blocks, XCD-swizzled in-kernel
    dim3 block(256);
    GatherVertical_40656160424516_kernel<<<grid, block, 0, stream>>>(in, w, bs, out);
}

// Round 6
// 344.501 us; speedup vs baseline: 1.4886x; 1.4886x over previous
//
#include <hip/hip_runtime.h>
#include <hip/hip_bf16.h>

// out[b,k,oc,x] = sum_i W[k,oc,i] * in[b,i,k,x] + bias[k,oc]
// B=4096, Cin=Cout=128, K(offsets)=9, X=9.
// Memory-bound: ~290 MB HBM traffic -> ~46us floor @6.3TB/s; ~3.3TB/s shown
// reachable (R5's spill traffic sustained it).
// R1: XCD swizzle + W direct from global.                (158us)
// R2: deep-MLP staging -> null. Load MLP exonerated.     (164us)
// R3: LDS-relayout coalesced stores -> -13%.             (143us)
// R4: contiguous-read all-k blocks -> regression.        (249us)
// R5: 8 blocks/CU under a 64-reg budget -> spill.        (322us)
// R6: within-wave pipeline (reg-staged prefetch, raw s_barrier + lgkm-only
//     drains) -> FAILED on LDS slot swap (x=7/x=8), not on the pipeline.
// R7: R6 with staging slots in correct x-order. Structure unchanged:
//     block = one btile x 3 k-tiles; next tile's 6 input loads issue under
//     current tile's MFMA+epilogue (W loads issued BEFORE them so the
//     W-convert's FIFO vmcnt wait completes without draining the prefetch;
//     sched_barrier(0) pins order); barriers never drain vmcnt.

#define NB    4096
#define CINC  128
#define COUTC 128
#define NK    9
#define NX    9
#define BT    8                // b's per tile
#define NCOL  (BT * NX)        // 72 cols
#define LDK   136              // padded i-stride (shorts)
#define ROWF  (NK * NX)        // 81 floats per (b,i) row
#define OUTK  (COUTC * NX)     // 1152 floats per (b,k)
#define OUTB  (NK * OUTK)
#define KG    3                // k-tiles per block

typedef __attribute__((ext_vector_type(8))) short short8;
typedef __attribute__((ext_vector_type(4))) float floatx4;
typedef __attribute__((ext_vector_type(2))) float floatx2;

struct F4 { float x, y, z, w; };   // 16B payload, 4B-aligned -> global_load_dwordx4

__device__ __forceinline__ short f2bf(float f) {
    union { float f; unsigned u; } v; v.f = f;
    unsigned r = v.u + 0x7fff + ((v.u >> 16) & 1);  // RNE; inputs finite normals
    return (short)(r >> 16);
}
__device__ __forceinline__ unsigned pack2(float lo, float hi) {
    return (unsigned)(unsigned short)f2bf(lo) | ((unsigned)(unsigned short)f2bf(hi) << 16);
}

__global__ __launch_bounds__(512, 4) void GatherVertical_40656160424516_kernel(
    const float* __restrict__ in, const float* __restrict__ w,
    const float* __restrict__ bias, float* __restrict__ out)
{
    // Il: bf16 [col=bl*9+x : 72][i : LDK]  = 19584 B   (MFMA operand tile)
    // Ol: f32  [bl : 8][oc : 128][x : 9]   = 36864 B   (epilogue relayout)
    // disjoint regions (pipeline overlaps their lifetimes); 56448 B -> 2 blk/CU.
    __shared__ __align__(16) char smem[NCOL * LDK * 2 + BT * OUTK * 4];
    short* Il = (short*)smem;
    float* Ol = (float*)(smem + NCOL * LDK * 2);

    const int t = threadIdx.x;

    // XCD swizzle: the 3 kg-siblings of a btile share one XCD's L2
    // (k-adjacent tiles share input cache lines). grid 1536 % 8 == 0: bijective.
    const int j = blockIdx.x;
    const int xcd = j & 7;
    const int slot = j >> 3;          // 0..191
    const int kg = slot % 3;
    const int btg = slot / 3;         // 0..63
    const int btile = btg * 8 + xcd;  // 0..511
    const int b0 = btile * BT;
    const int k0 = kg * KG;

    const int lane = t & 63;
    const int wv = t >> 6;            // 0..7: M-tile (16 oc) AND staged b-row
    const int lc = lane & 15;
    const int quad = lane >> 4;
    const int oc_base = wv * 16;

    // ---- staging decomposition: wave wv owns b-row bl=wv; lane owns rows
    // i = 2*lane, 2*lane+1. Per tile: 6 wide loads (2x 16B + 4B per row),
    // 9 packed b32 LDS writes at one base + imm offsets (2-way banks = free).
    const int i0 = lane * 2;
    const float* rowp = in + ((size_t)(b0 + wv) * CINC + i0) * ROWF;

    F4 sa0, sb0, sa1, sb1; float sc0, sc1;
    auto issue_in = [&](int k) {
        const float* p0 = rowp + k * NX;   // row i0, k-slice: 9 floats
        const float* p1 = p0 + ROWF;       // row i0+1
        sa0 = *(const F4*)p0; sb0 = *(const F4*)(p0 + 4); sc0 = p0[8];
        sa1 = *(const F4*)p1; sb1 = *(const F4*)(p1 + 4); sc1 = p1[8];
    };
    issue_in(k0);

    unsigned* Iw = (unsigned*)Il;
    const int wbase = ((wv * 9) * LDK + i0) >> 1;   // u32 index; +x*68 per x

    for (int tk = 0; tk < KG; ++tk) {
        const int k = k0 + tk;

        // ---- staged regs -> Il in x-order: p[0..3]=sa, p[4..7]=sb, p[8]=sc.
        // (compiler inserts the counted vmcnt wait for the prefetch here)
        Iw[wbase + 0 * 68] = pack2(sa0.x, sa1.x);
        Iw[wbase + 1 * 68] = pack2(sa0.y, sa1.y);
        Iw[wbase + 2 * 68] = pack2(sa0.z, sa1.z);
        Iw[wbase + 3 * 68] = pack2(sa0.w, sa1.w);
        Iw[wbase + 4 * 68] = pack2(sb0.x, sb1.x);
        Iw[wbase + 5 * 68] = pack2(sb0.y, sb1.y);
        Iw[wbase + 6 * 68] = pack2(sb0.z, sb1.z);
        Iw[wbase + 7 * 68] = pack2(sb0.w, sb1.w);
        Iw[wbase + 8 * 68] = pack2(sc0, sc1);

        asm volatile("s_waitcnt lgkmcnt(0)" ::: "memory");
        __builtin_amdgcn_s_barrier();

        // ---- W + bias loads FIRST (oldest in VMEM FIFO: their wait below
        // completes without draining the input prefetch issued after them)
        const float* wp = w + k * (COUTC * CINC) + (oc_base + lc) * CINC + quad * 8;
        float4 w0[4], w1[4];
        #pragma unroll
        for (int s = 0; s < 4; ++s) {
            w0[s] = *(const float4*)(wp + s * 32);
            w1[s] = *(const float4*)(wp + s * 32 + 4);
        }
        const float* bp = bias + k * COUTC + oc_base + quad * 4;
        float bsv[4];
        #pragma unroll
        for (int r = 0; r < 4; ++r) bsv[r] = bp[r];
        __builtin_amdgcn_sched_barrier(0);
        // ---- input prefetch for next tile: in flight through MFMA+epilogue
        if (tk < KG - 1) issue_in(k + 1);
        __builtin_amdgcn_sched_barrier(0);

        // ---- convert W (vmcnt wait reaches only the W loads)
        short8 afr[4];
        #pragma unroll
        for (int s = 0; s < 4; ++s) {
            short8 a;
            a[0] = f2bf(w0[s].x); a[1] = f2bf(w0[s].y);
            a[2] = f2bf(w0[s].z); a[3] = f2bf(w0[s].w);
            a[4] = f2bf(w1[s].x); a[5] = f2bf(w1[s].y);
            a[6] = f2bf(w1[s].z); a[7] = f2bf(w1[s].w);
            afr[s] = a;
        }

        // ---- MFMA: M=16 (wave's oc), K=128, N=72: 4 full col-tiles + half
        // tile (lanes lc>=8 duplicate col 64+(lc&7); outputs 72..79 discarded)
        floatx4 acc[5];
        #pragma unroll
        for (int n = 0; n < 5; ++n) acc[n] = (floatx4){0.f, 0.f, 0.f, 0.f};
        #pragma unroll
        for (int s = 0; s < 4; ++s) {
            const int kof = s * 32 + quad * 8;
            #pragma unroll
            for (int n = 0; n < 5; ++n) {
                const int col = (n < 4) ? (n * 16 + lc) : (64 + (lc & 7));
                short8 bfr = *(const short8*)&Il[col * LDK + kof];
                acc[n] = __builtin_amdgcn_mfma_f32_16x16x32_bf16(afr[s], bfr, acc[n], 0, 0, 0);
            }
        }

        // ---- scatter acc+bias -> Ol[bl][oc][x]
        // C/D: col(lane&15)=nx -> (bl=nx/9, x=nx%9); row(quad*4+r)=oc offset.
        #pragma unroll
        for (int n = 0; n < 4; ++n) {
            int nx = n * 16 + lc;
            int bl = nx / 9;
            int x = nx - bl * 9;
            float* op = Ol + (bl * COUTC + oc_base + quad * 4) * NX + x;
            #pragma unroll
            for (int r = 0; r < 4; ++r) op[r * NX] = acc[n][r] + bsv[r];
        }
        if (lc < 8) {                       // n=4 valid cols: nx=64..71 -> bl=7, x=1..8
            int x = lc + 1;
            float* op = Ol + (7 * COUTC + oc_base + quad * 4) * NX + x;
            #pragma unroll
            for (int r = 0; r < 4; ++r) op[r * NX] = acc[4][r] + bsv[r];
        }

        asm volatile("s_waitcnt lgkmcnt(0)" ::: "memory");
        __builtin_amdgcn_s_barrier();

        // ---- copy Ol -> out: wave wv streams row bl=wv, 1152 contiguous
        // floats (4x dwordx4 + dwordx2); stores stay in flight into next tile.
        const float* src = Ol + wv * OUTK;
        float* dst = out + (size_t)(b0 + wv) * OUTB + k * OUTK;
        #pragma unroll
        for (int s = 0; s < 4; ++s) {
            floatx4 v = *(const floatx4*)(src + s * 256 + lane * 4);
            *(floatx4*)(dst + s * 256 + lane * 4) = v;
        }
        floatx2 v2 = *(const floatx2*)(src + 1024 + lane * 2);
        *(floatx2*)(dst + 1024 + lane * 2) = v2;
        // next iteration's Il writes are safe: Il/Ol disjoint; the lgkm(0)
        // drain before barrier1 (loop top) covers this copy's Ol ds_reads.
    }
}

extern "C" void kernel_launch(void* const* d_in, const int* in_sizes, int n_in,
                              void* d_out, int out_size, void* d_ws, size_t ws_size,
                              hipStream_t stream) {
    const float* in  = (const float*)d_in[0];
    const float* w   = (const float*)d_in[1];
    const float* bs  = (const float*)d_in[2];
    float* out = (float*)d_out;
    dim3 grid((NB / BT) * (NK / KG));   // 512 btiles x 3 kgroups = 1536 blocks
    dim3 block(512);
    GatherVertical_40656160424516_kernel<<<grid, block, 0, stream>>>(in, w, bs, out);
}